// Round 7
// baseline (933.933 us; speedup 1.0000x reference)
//
#include <hip/hip_runtime.h>

#define NN 100000   // nodes
#define NE 400000   // edges per relation
#define NR 8        // relations
#define DD 128      // feature dim
#define NBK 391     // buckets per relation: ceil(NN/256)
#define BCAP 1536   // capacity per bucket region (mean 1024, +16 sigma)
#define P1B 32      // phase-1 blocks per relation
#define NNP 100096  // padded rows (tile over-read safety)
#define NTILE 6250  // NN/16 (exact)

typedef unsigned short ushort_t;
using short8  = __attribute__((ext_vector_type(8))) short;
using f32x4   = __attribute__((ext_vector_type(4))) float;

__device__ __forceinline__ ushort_t f2bf(float f) {
  union { float f; unsigned u; } v; v.f = f;
  unsigned u = v.u;
  return (ushort_t)((u + 0x7FFFu + ((u >> 16) & 1u)) >> 16);  // RNE
}
__device__ __forceinline__ float bf2f(unsigned hs) {
  union { unsigned u; float f; } v; v.u = hs << 16;
  return v.f;
}

// ---------------- conversion ----------------
__global__ __launch_bounds__(256) void f32_to_bf16_kernel(const float* __restrict__ in,
                                                          ushort_t* __restrict__ out, int n4) {
  int t = blockIdx.x * 256 + threadIdx.x;
  if (t < n4) {
    float4 f = ((const float4*)in)[t];
    uint2 p;
    p.x = (unsigned)f2bf(f.x) | ((unsigned)f2bf(f.y) << 16);
    p.y = (unsigned)f2bf(f.z) | ((unsigned)f2bf(f.w) << 16);
    ((uint2*)out)[t] = p;
  }
}

// fc_src_w [3][8][128][128] f32 -> Wfrag [3][8(kc)][4(s)][8(nt)][64(lane)] uint4 (8 bf16)
// Fragment-ordered B operand: lane (m16,kq) holds W[o = nt*16+m16][d = (s*4+kq)*8 .. +7].
__global__ __launch_bounds__(256) void wfrag_kernel(const float* __restrict__ in, uint4* __restrict__ out) {
  int t = blockIdx.x * 256 + threadIdx.x;   // 3*8*4*8*64 = 49152
  int lane = t & 63;
  int nt = (t >> 6) & 7;
  int s  = (t >> 9) & 3;
  int kc = (t >> 11) & 7;
  int l  = t >> 14;
  int m16 = lane & 15, kq = lane >> 4;
  int o = nt * 16 + m16;
  int chunk = s * 4 + kq;
  const float* p = in + ((((size_t)l * 8 + kc) * 128 + o) * 128 + chunk * 8);
  uint4 v;
  v.x = (unsigned)f2bf(p[0]) | ((unsigned)f2bf(p[1]) << 16);
  v.y = (unsigned)f2bf(p[2]) | ((unsigned)f2bf(p[3]) << 16);
  v.z = (unsigned)f2bf(p[4]) | ((unsigned)f2bf(p[5]) << 16);
  v.w = (unsigned)f2bf(p[6]) | ((unsigned)f2bf(p[7]) << 16);
  out[t] = v;
}

// ---------------- CSR build: phase 1 — bucket by dst>>8, LDS-staged 64B flushes ----------------
__global__ __launch_bounds__(256) void bucket_kernel(const int* __restrict__ edge_dst,
                                                     const int* __restrict__ edge_src,
                                                     int* __restrict__ gcur, unsigned* __restrict__ E1) {
  __shared__ unsigned stage[NBK][32];
  __shared__ int lcnt[NBK];
  int r   = blockIdx.x >> 5;
  int blk = blockIdx.x & 31;
  int t = threadIdx.x;
  for (int i = t; i < NBK; i += 256) lcnt[i] = 0;
  __syncthreads();
  const int per = NE / P1B;          // 12500
  int e0 = blk * per, e1 = e0 + per;
  const int* ed = edge_dst + (size_t)r * NE;
  const int* es = edge_src + (size_t)r * NE;
  int* gc = gcur + r * NBK;
  unsigned* E1r = E1 + (size_t)r * NBK * BCAP;
  for (int base = e0; base < e1; base += 4096) {
    int lim = min(base + 4096, e1);
    for (int e = base + t; e < lim; e += 256) {
      int d = ed[e];
      unsigned val = ((unsigned)es[e] << 8) | (unsigned)(d & 255);
      int b = d >> 8;
      int slot = atomicAdd(&lcnt[b], 1);
      if (slot < 32) stage[b][slot] = val;
      else {  // rare overflow: direct spill
        int p = atomicAdd(&gc[b], 1);
        if (p < BCAP) E1r[(size_t)b * BCAP + p] = val;
      }
    }
    __syncthreads();
    for (int b = t; b < NBK; b += 256) {
      int c = lcnt[b]; if (c > 32) c = 32;
      int nf = c & ~15;               // flush multiples of 16 (64B)
      if (nf) {
        int p = atomicAdd(&gc[b], nf);
        for (int k = 0; k < nf; k++)
          if (p + k < BCAP) E1r[(size_t)b * BCAP + p + k] = stage[b][k];
        for (int k = nf; k < c; k++) stage[b][k - nf] = stage[b][k];
      }
      lcnt[b] = c - nf;
    }
    __syncthreads();
  }
  for (int b = t; b < NBK; b += 256) {
    int c = lcnt[b]; if (c > 32) c = 32;
    if (c) {
      int p = atomicAdd(&gc[b], c);
      for (int k = 0; k < c; k++)
        if (p + k < BCAP) E1r[(size_t)b * BCAP + p + k] = stage[b][k];
    }
  }
}

// ---------------- CSR build: scan bucket counts -> bucket base offsets ----------------
__global__ __launch_bounds__(256) void bscan_kernel(const int* __restrict__ gcur, int* __restrict__ bbase) {
  __shared__ int ps[256];
  int t = threadIdx.x;
  int vals[13];
  int s = 0;
#pragma unroll
  for (int i = 0; i < 13; i++) {
    int idx = t * 13 + i;
    int c = (idx < NR * NBK) ? min(gcur[idx], BCAP) : 0;
    vals[i] = s; s += c;
  }
  ps[t] = s;
  __syncthreads();
  for (int off = 1; off < 256; off <<= 1) {
    int x = (t >= off) ? ps[t - off] : 0;
    __syncthreads();
    ps[t] += x;
    __syncthreads();
  }
  int excl = ps[t] - s;
#pragma unroll
  for (int i = 0; i < 13; i++) {
    int idx = t * 13 + i;
    if (idx < NR * NBK) bbase[idx] = excl + vals[i];
  }
}

// ---------------- CSR build: phase 2 — per-bucket exact CSR ----------------
__global__ __launch_bounds__(256) void csr_kernel(const unsigned* __restrict__ E1, const int* __restrict__ gcur,
                                                  const int* __restrict__ bbase,
                                                  int* __restrict__ offs, int* __restrict__ srcs) {
  __shared__ unsigned ent[BCAP];
  __shared__ int cnt[256], pref[256], excl_s[256];
  int rb = blockIdx.x;                 // r*NBK + b
  int b = rb % NBK, r = rb / NBK;
  int t = threadIdx.x;
  int n = min(gcur[rb], BCAP);
  const unsigned* src = E1 + (size_t)rb * BCAP;
  for (int i = t; i < n; i += 256) ent[i] = src[i];
  cnt[t] = 0;
  __syncthreads();
  for (int i = t; i < n; i += 256) atomicAdd(&cnt[ent[i] & 255], 1);
  __syncthreads();
  int v = cnt[t];
  pref[t] = v;
  __syncthreads();
  for (int off = 1; off < 256; off <<= 1) {
    int x = (t >= off) ? pref[t - off] : 0;
    __syncthreads();
    pref[t] += x;
    __syncthreads();
  }
  int excl = pref[t] - v;
  excl_s[t] = excl;
  int gb = bbase[rb];
  int d = b * 256 + t;
  if (d < NN) offs[(size_t)r * NN + d] = gb + excl;
  if (rb == NR * NBK - 1 && t == 0) offs[(size_t)NR * NN] = NR * NE;
  cnt[t] = 0;
  __syncthreads();
  for (int i = t; i < n; i += 256) {
    unsigned e = ent[i];
    int dl = e & 255;
    int p = atomicAdd(&cnt[dl], 1);
    srcs[gb + excl_s[dl] + p] = (int)(e >> 8);
  }
}

// ---------------- attention vectors for ALL layers -> bf16 UV table [3][16][128] ----------------
__global__ __launch_bounds__(128) void uv_all_kernel(const float* __restrict__ Wsrc, const float* __restrict__ Wdst,
                                                     const float* __restrict__ al, const float* __restrict__ ar,
                                                     ushort_t* __restrict__ uvb) {
  int rl = blockIdx.x, j = threadIdx.x;   // rl = l*8 + r over 24
  int l = rl >> 3, r = rl & 7;
  const float* Ws = Wsrc + (size_t)rl * DD * DD;
  const float* Wd = Wdst + (size_t)rl * DD * DD;
  float su = 0.f, sv = 0.f;
  for (int i = 0; i < DD; i++) {
    su += al[rl * DD + i] * Ws[i * DD + j];
    sv += ar[rl * DD + i] * Wd[i * DD + j];
  }
  uvb[((size_t)l * 16 + r) * DD + j]     = f2bf(su);
  uvb[((size_t)l * 16 + 8 + r) * DD + j] = f2bf(sv);
}

// ---------------- elr via MFMA: ELR[16][NN] = (xb @ UV^T)^T ----------------
__global__ __launch_bounds__(256) void elr_kernel(const ushort_t* __restrict__ xb,
                                                  const ushort_t* __restrict__ uvb,
                                                  float* __restrict__ elr) {
  int t = threadIdx.x;
  int lane = t & 63, wave = t >> 6;
  int m16 = lane & 15, kq = lane >> 4;
  int n0 = blockIdx.x * 64 + wave * 16;
  const short8* Ag = (const short8*)xb;    // 16 chunks per row
  const short8* Bg = (const short8*)uvb;   // 16 chunks per row
  int bbase = m16 * 16 + kq;
  short8 b0 = Bg[bbase + 0];
  short8 b1 = Bg[bbase + 4];
  short8 b2 = Bg[bbase + 8];
  short8 b3 = Bg[bbase + 12];
  size_t abase = (size_t)(n0 + m16) * 16 + kq;
  short8 a0 = Ag[abase + 0];
  short8 a1 = Ag[abase + 4];
  short8 a2 = Ag[abase + 8];
  short8 a3 = Ag[abase + 12];
  f32x4 acc = (f32x4)(0.f);
  acc = __builtin_amdgcn_mfma_f32_16x16x32_bf16(a0, b0, acc, 0, 0, 0);
  acc = __builtin_amdgcn_mfma_f32_16x16x32_bf16(a1, b1, acc, 0, 0, 0);
  acc = __builtin_amdgcn_mfma_f32_16x16x32_bf16(a2, b2, acc, 0, 0, 0);
  acc = __builtin_amdgcn_mfma_f32_16x16x32_bf16(a3, b3, acc, 0, 0, 0);
  // C/D: col = m16 (ELR row), tile row = kq*4 + i (node)
#pragma unroll
  for (int i = 0; i < 4; i++) {
    int n = n0 + kq * 4 + i;
    if (n < NN) elr[(size_t)m16 * NN + n] = acc[i];
  }
}

// ---------------- edge softmax + aggregation (R0-proven store: node-major, coalesced) ----------------
// One 16-lane group per (node, relation). AGG layout [n][rg][chunk]: each group stores
// one contiguous 256B row; a block stores 4KB contiguous (NN%16==0 so no rg-crossing).
// PLAIN full-line stores: no write-allocate reads (R6's 16B-scatter store doubled both
// FETCH and WRITE via partial-line write-allocate), AGG stays LLC-resident for gemm2.
__global__ __launch_bounds__(256) void edge_kernel(const int* __restrict__ srcs, const int* __restrict__ offs,
                                                   const float* __restrict__ el, const float* __restrict__ er,
                                                   const ushort_t* __restrict__ xb, uint4* __restrict__ agg) {
  int t = threadIdx.x;
  int lane16 = t & 15;
  int id = blockIdx.x * 16 + (t >> 4);   // over NN*NR
  int n = id % NN;
  int rg = id / NN;
  int k0 = offs[(size_t)rg * NN + n], k1 = offs[(size_t)rg * NN + n + 1];
  float acc[8];
#pragma unroll
  for (int i = 0; i < 8; i++) acc[i] = 0.f;
  if (k1 > k0) {
    float erd = er[(size_t)rg * NN + n];
    const float* elr = el + (size_t)rg * NN;
    float denom = 0.f;
    for (int e = k0; e < k1; e++) {
      int s = srcs[e];
      float x = elr[s] + erd;
      x = x > 0.f ? x : 0.2f * x;
      float w = __expf(x);
      denom += w;
      uint4 p = ((const uint4*)(xb + (size_t)s * DD))[lane16];
      acc[0] += w * bf2f(p.x & 0xffffu);
      acc[1] += w * bf2f(p.x >> 16);
      acc[2] += w * bf2f(p.y & 0xffffu);
      acc[3] += w * bf2f(p.y >> 16);
      acc[4] += w * bf2f(p.z & 0xffffu);
      acc[5] += w * bf2f(p.z >> 16);
      acc[6] += w * bf2f(p.w & 0xffffu);
      acc[7] += w * bf2f(p.w >> 16);
    }
    float inv = 1.f / denom;
#pragma unroll
    for (int i = 0; i < 8; i++) acc[i] *= inv;
  }
  uint4 o;
  o.x = (unsigned)f2bf(acc[0]) | ((unsigned)f2bf(acc[1]) << 16);
  o.y = (unsigned)f2bf(acc[2]) | ((unsigned)f2bf(acc[3]) << 16);
  o.z = (unsigned)f2bf(acc[4]) | ((unsigned)f2bf(acc[5]) << 16);
  o.w = (unsigned)f2bf(acc[6]) | ((unsigned)f2bf(acc[7]) << 16);
  agg[((size_t)n * NR + rg) * 16 + lane16] = o;   // node-major, 256B/group contiguous
}

// ---------------- zero-LDS zero-barrier streaming MFMA GEMM (node-major A) ----------------
// a-frag for lane (m16,kq), tile row m16, rel kc, slice s lives at
//   AGG + ((tile*16+m16)*NR + kc)*256B + (s*4+kq)*16B.
// Per wave-instruction: 16 distinct 64B lines, each fully consumed by its 4 kq-lanes
// (kq spans s*64..s*64+63 of the row) -> same line count & bytes as a contiguous 1KB
// load, only the lane->addr permutation differs. No transpose needed anywhere.
// Each wave owns 2 adjacent tiles (32 rows): b-frags (L2-hot Wfrag) reused x2.
__global__ __launch_bounds__(256) void gemm2_kernel(
    const uint4* __restrict__ AGG, const uint4* __restrict__ Wfrag,
    const float* __restrict__ bias, ushort_t* __restrict__ xout,
    float* __restrict__ dout, int relu, int last) {
  int t = threadIdx.x;
  int lane = t & 63, wave = t >> 6;
  int gw = blockIdx.x * 4 + wave;          // wave-job: 2 tiles (32 rows)
  if (gw >= NTILE / 2) return;
  int m16 = lane & 15, kq = lane >> 4;
  float bv[8];
#pragma unroll
  for (int nt = 0; nt < 8; nt++) bv[nt] = bias[m16 + 16 * nt];
  // lane's row base for tile0/tile1: node = 2*gw*16 + m16 (tile0), +16 (tile1)
  const uint4* an0 = AGG + ((size_t)(2 * gw * 16 + m16) * NR) * 16 + kq;
  const uint4* an1 = an0 + (size_t)16 * NR * 16;
  f32x4 acc0[8], acc1[8];
#pragma unroll
  for (int nt = 0; nt < 8; nt++) { acc0[nt] = (f32x4)(0.f); acc1[nt] = (f32x4)(0.f); }
#pragma unroll 1
  for (int kc = 0; kc < NR; kc++) {
    short8 a0[4], a1[4];
#pragma unroll
    for (int s = 0; s < 4; s++) {
      a0[s] = *reinterpret_cast<const short8*>(an0 + kc * 16 + s * 4);
      a1[s] = *reinterpret_cast<const short8*>(an1 + kc * 16 + s * 4);
    }
    const uint4* wfp = Wfrag + (size_t)kc * 2048 + lane;
#pragma unroll
    for (int s = 0; s < 4; s++) {
#pragma unroll
      for (int nt = 0; nt < 8; nt++) {
        short8 bf = *reinterpret_cast<const short8*>(wfp + (s * 8 + nt) * 64);
        acc0[nt] = __builtin_amdgcn_mfma_f32_16x16x32_bf16(a0[s], bf, acc0[nt], 0, 0, 0);
        acc1[nt] = __builtin_amdgcn_mfma_f32_16x16x32_bf16(a1[s], bf, acc1[nt], 0, 0, 0);
      }
    }
  }
  // epilogue: C/D col = m16 + 16*nt, row = tile*16 + kq*4 + i
  int r0 = 2 * gw * 16 + kq * 4;
#pragma unroll
  for (int i = 0; i < 4; i++) {
    int rowa = r0 + i, rowb = r0 + 16 + i;
#pragma unroll
    for (int nt = 0; nt < 8; nt++) {
      float va = acc0[nt][i] + bv[nt];
      float vb = acc1[nt][i] + bv[nt];
      if (relu) { va = fmaxf(va, 0.f); vb = fmaxf(vb, 0.f); }
      int col = m16 + 16 * nt;
      if (last) {
        dout[(size_t)rowa * DD + col] = va;
        dout[(size_t)rowb * DD + col] = vb;
      } else {
        xout[(size_t)rowa * DD + col] = f2bf(va);
        xout[(size_t)rowb * DD + col] = f2bf(vb);
      }
    }
  }
}

extern "C" void kernel_launch(void* const* d_in, const int* in_sizes, int n_in,
                              void* d_out, int out_size, void* d_ws, size_t ws_size,
                              hipStream_t stream) {
  const float* h        = (const float*)d_in[0];
  const int*   edge_src = (const int*)d_in[1];
  const int*   edge_dst = (const int*)d_in[2];
  const float* fc_src_w = (const float*)d_in[3];
  const float* fc_dst_w = (const float*)d_in[4];
  const float* attn_l   = (const float*)d_in[5];
  const float* attn_r   = (const float*)d_in[6];
  const float* h_bias   = (const float*)d_in[7];
  float* dout = (float*)d_out;
  (void)in_sizes; (void)n_in; (void)out_size; (void)ws_size;

  char* base = (char*)d_ws;
  size_t off = 0;
  auto alloc = [&](size_t bytes) -> void* {
    void* p = base + off;
    off += (bytes + 255) & ~(size_t)255;
    return p;
  };
  // Persistent region (~49.7 MB)
  ushort_t* xb    = (ushort_t*)alloc((size_t)NNP * DD * 2);   // single feature buffer (in-place across layers)
  float*    ELR   = (float*)   alloc((size_t)16 * NN * 4);    // rows 0-7: el_r, 8-15: er_r
  ushort_t* uvb   = (ushort_t*)alloc((size_t)3 * 16 * DD * 2);
  uint4*    Wfrag = (uint4*)   alloc((size_t)3 * NR * 4 * 8 * 64 * 16);  // fragment-ordered W
  int*      offs  = (int*)     alloc(((size_t)NR * NN + 1) * 4);
  int*      gcur  = (int*)     alloc((size_t)NR * NBK * 4);
  int*      bbase = (int*)     alloc((size_t)NR * NBK * 4);
  int*      srcs  = (int*)     alloc((size_t)NR * NE * 4);
  // Scratch union: E1 (19.2 MB, dead after csr_kernel) overlaps AGG (204.8 MB).
  size_t e1_bytes  = (size_t)NR * NBK * BCAP * 4;
  size_t agg_bytes = (size_t)NN * NR * 16 * 16;
  void* scratch = alloc(agg_bytes > e1_bytes ? agg_bytes : e1_bytes);
  unsigned* E1  = (unsigned*)scratch;
  uint4*    AGG = (uint4*)scratch;
  // total ~254.5 MB (fits: R0's fused path proved >= 273 MB available)

  // ---- CSR build ----
  (void)hipMemsetAsync(gcur, 0, (size_t)NR * NBK * 4, stream);
  // zero pad rows of feature buffer (elr_kernel over-reads up to NNP)
  (void)hipMemsetAsync(xb + (size_t)NN * DD, 0, (size_t)(NNP - NN) * DD * 2, stream);
  bucket_kernel<<<NR * P1B, 256, 0, stream>>>(edge_dst, edge_src, gcur, E1);
  bscan_kernel<<<1, 256, 0, stream>>>(gcur, bbase);
  csr_kernel<<<NR * NBK, 256, 0, stream>>>(E1, gcur, bbase, offs, srcs);

  f32_to_bf16_kernel<<<(NN * DD / 4 + 255) / 256, 256, 0, stream>>>(h, xb, NN * DD / 4);
  wfrag_kernel<<<3 * NR * 4 * 8 * 64 / 256, 256, 0, stream>>>(fc_src_w, Wfrag);
  uv_all_kernel<<<3 * NR, 128, 0, stream>>>(fc_src_w, fc_dst_w, attn_l, attn_r, uvb);

  const float* el = ELR;
  const float* er = ELR + (size_t)8 * NN;
  for (int l = 0; l < 3; l++) {
    elr_kernel<<<(NN + 63) / 64, 256, 0, stream>>>(xb, uvb + (size_t)l * 16 * DD, ELR);
    edge_kernel<<<NN * NR / 16, 256, 0, stream>>>(srcs, offs, el, er, xb, AGG);
    gemm2_kernel<<<(NTILE / 2 + 3) / 4, 256, 0, stream>>>(
        AGG, Wfrag + (size_t)l * NR * 4 * 8 * 64, h_bias + (size_t)l * DD,
        xb, dout, (l < 2) ? 1 : 0, (l == 2) ? 1 : 0);
  }
}